// Round 2
// 227.787 us; speedup vs baseline: 1.0850x; 1.0850x over previous
//
#include <hip/hip_runtime.h>

// ---------------- problem constants ----------------
#define NTOK   32768
#define DIM    512            // bytes per fp8 row too
#define NCODE  4096
#define NELEM  (NTOK*DIM)     // 16777216
#define COMMIT 0.25
#define ESCALE 8192.0f        // 2^13: lifts emb (~2.4e-4) into e4m3 normal range
#define EINV   (1.0f/4096.0f) // 2^-12: score = en - 2*(acc/8192) = en - acc*2^-12
#define KSCL   262144.0f      // 2^18 key quantizer
#define KOFF   65536.0f       // 0.25 * 2^18 (covers |s| <= 0.25 hard bound)

// ---------------- ws layout (bytes) ----------------
#define OFF_Z8      0ULL              // fp8 z: 16777216
#define OFF_E8      16777216ULL       // fp8 e*8192: 2097152
#define OFF_EN32    18874368ULL       // float[4096] = 16384
#define OFF_ROWMIN  18890752ULL       // u32[32768] = 131072 (packed key20|code12)
#define OFF_COUNTS  19021824ULL       // u32[4096] = 16384
#define OFF_SSE     19038208ULL       // double[256] = 2048

typedef int   v8i  __attribute__((ext_vector_type(8)));
typedef float v16f __attribute__((ext_vector_type(16)));

#define GLOBAL_AS __attribute__((address_space(1)))
#define LDS_AS    __attribute__((address_space(3)))

__device__ __forceinline__ void gld16(const void* g, void* l) {
    // async global->LDS, 16B/lane; LDS dest = wave-uniform base + lane*16
    __builtin_amdgcn_global_load_lds((const GLOBAL_AS unsigned int*)g,
                                     (LDS_AS unsigned int*)l, 16, 0, 0);
}

// ---------------- 1. fp32 -> fp8 e4m3 conversion (+ counts/sse init) ----------
__global__ void conv_kernel(const float* __restrict__ z, const float* __restrict__ e,
                            unsigned* __restrict__ z8, unsigned* __restrict__ e8,
                            unsigned* __restrict__ counts, double* __restrict__ sse) {
    const int ZI = NELEM / 16;                 // 1048576 (16 floats -> 16 fp8 per thread)
    const int TI = ZI + (NCODE * DIM) / 16;    // +131072
    int i = blockIdx.x * blockDim.x + threadIdx.x;
    if (i < NCODE) counts[i] = 0u;
    if (i < 256)   sse[i] = 0.0;
    if (i >= TI) return;
    const float4* src; unsigned* dst; int j; float sc;
    if (i < ZI) { src = (const float4*)z; dst = z8; j = i; sc = 1.0f; }
    else        { src = (const float4*)e; dst = e8; j = i - ZI; sc = ESCALE; }
    uint4 o;
#pragma unroll
    for (int q = 0; q < 4; q++) {
        float4 v = src[j * 4 + q];
        int r = 0;
        r = __builtin_amdgcn_cvt_pk_fp8_f32(v.x * sc, v.y * sc, r, false);
        r = __builtin_amdgcn_cvt_pk_fp8_f32(v.z * sc, v.w * sc, r, true);
        (&o.x)[q] = (unsigned)r;
    }
    ((uint4*)dst)[j] = o;
}

// ---------------- 2. ||e_k||^2 (exact f32 via f64 accumulate) ----------------
__global__ void enorm_kernel(const float* __restrict__ emb, float* __restrict__ en32) {
    int gw = (blockIdx.x * blockDim.x + threadIdx.x) >> 6;   // wave id = code
    int lane = threadIdx.x & 63;
    if (gw >= NCODE) return;
    const float4* p = (const float4*)(emb + (size_t)gw * DIM);
    float4 a = p[lane * 2], b = p[lane * 2 + 1];
    double s = (double)a.x*a.x + (double)a.y*a.y + (double)a.z*a.z + (double)a.w*a.w
             + (double)b.x*b.x + (double)b.y*b.y + (double)b.z*b.z + (double)b.w*b.w;
    for (int off = 32; off; off >>= 1) s += __shfl_down(s, off);
    if (lane == 0) en32[gw] = (float)s;
}

// ---------------- 3. persistent-code-loop MX-fp8 score pass -----------------
// One block = 64 token rows x all 4096 codes. v2 pipeline:
//   - z tile staged to LDS once, A-fragments hoisted to 64 VGPRs, then the z
//     LDS region is reused as the SECOND e-tile buffer (double-buffered E).
//   - e-tile t+2 staged (8 gld16/wave) at the END of iteration t; iteration
//     entry waits s_waitcnt vmcnt(8) (the 8 newest ops are tile t+1's) + raw
//     s_barrier -> the DMA has a full iteration of compute to land. vmcnt is
//     never drained to 0 in the main loop (only on the peeled last iter).
//   - en32 staged to LDS once so the vmcnt counter sees ONLY tile gld16s.
// LDS: 2x32KB buffers + 16KB en = 80KB -> exactly 2 blocks/CU (partner block
// hides the remaining barrier time). Per-iter LDS reads halve (B only).
// LDS rows 512B granule-swizzled: logical granule g of row m at slot g^(m&31)
// -> every b128 read hits 32 distinct granule positions (conflict-free).
__global__ __launch_bounds__(256, 2)
void score_pass(const unsigned char* __restrict__ z8, const unsigned char* __restrict__ e8,
                const float* __restrict__ en32,
                unsigned* __restrict__ rowmin) {
    __shared__ __align__(16) unsigned char sB0[64 * 512];   // e-tile buffer A
    __shared__ __align__(16) unsigned char sB1[64 * 512];   // z staging, then e buffer B
    __shared__ __align__(16) float sEn[NCODE];               // 16KB code norms
    const int tid = threadIdx.x;
    const int row0 = blockIdx.x * 64;    // token rows of this block
    const int wv = tid >> 6, ln = tid & 63;
    const int wm = wv & 1;               // row half  (32 rows)
    const int wn = wv >> 1;              // col half  (32 codes of the 64-code tile)
    const int c = ln & 31, h = ln >> 5;

    // ---- stage z tile into sB1: gld16 #q covers rows {2q, 2q+1}
#pragma unroll
    for (int s = 0; s < 8; s++) {
        int q = wv * 8 + s;
        int r = 2 * q + h;
        unsigned g = (unsigned)((ln & 31) ^ (r & 31));
        gld16(z8 + (size_t)(row0 + r) * 512 + g * 16u, sB1 + q * 1024);
    }
    // ---- stage en32 -> sEn: 16 x 1KB chunks, 4 per wave
#pragma unroll
    for (int s = 0; s < 4; s++) {
        int chunk = wv * 4 + s;
        gld16((const unsigned char*)en32 + chunk * 1024 + (unsigned)(ln * 16),
              (unsigned char*)sEn + chunk * 1024);
    }

    // per-lane e-tile source offsets (ct-invariant)
    unsigned eoff[8];
#pragma unroll
    for (int s = 0; s < 8; s++) {
        int q = wv * 8 + s;
        int r = 2 * q + h;               // row within 64-code tile
        unsigned g = (unsigned)((ln & 31) ^ (r & 31));
        eoff[s] = (unsigned)(r * 512) + g * 16u;
    }

    // pin issue order: z+en (12) strictly BEFORE tile0 (8), so vmcnt(8) below
    // provably means "z and en staged".
    __builtin_amdgcn_sched_barrier(0);

    // ---- stage e-tile 0 into sB0
#pragma unroll
    for (int s = 0; s < 8; s++)
        gld16(e8 + eoff[s], sB0 + (wv * 8 + s) * 1024);

    asm volatile("s_waitcnt vmcnt(8)" ::: "memory");   // z + en resident
    __builtin_amdgcn_s_barrier();

    // ---- hoist this wave's A fragments (32 z rows x K=512) into registers
    const int mrow = (wm * 32 + c) * 512;
    const int nrow = (wn * 32 + c) * 512;
    v8i za[8];
#pragma unroll
    for (int kt = 0; kt < 8; kt++) {
        int G = kt * 4 + 2 * h;
        uint4 x0 = *(const uint4*)(sB1 + mrow + (((G    ) ^ c) * 16));
        uint4 x1 = *(const uint4*)(sB1 + mrow + (((G + 1) ^ c) * 16));
        za[kt] = (v8i){(int)x0.x, (int)x0.y, (int)x0.z, (int)x0.w,
                       (int)x1.x, (int)x1.y, (int)x1.z, (int)x1.w};
    }
    asm volatile("s_waitcnt lgkmcnt(0)" ::: "memory");
    __builtin_amdgcn_s_barrier();        // all waves done with sB1 -> free

    // ---- stage e-tile 1 into sB1
#pragma unroll
    for (int s = 0; s < 8; s++)
        gld16(e8 + 32768 + eoff[s], sB1 + (wv * 8 + s) * 1024);

    unsigned runmin[16];
#pragma unroll
    for (int reg = 0; reg < 16; reg++) runmin[reg] = 0xFFFFFFFFu;

    for (int ct = 0; ct < 64; ct++) {
        // tile ct resident check: the 8 newest in-flight ops are tile ct+1's
        if (ct == 63) asm volatile("s_waitcnt vmcnt(0)" ::: "memory");
        else          asm volatile("s_waitcnt vmcnt(8)" ::: "memory");
        __builtin_amdgcn_s_barrier();

        const unsigned char* sB = (ct & 1) ? sB1 : sB0;
        float en = sEn[ct * 64 + wn * 32 + c];    // LDS (lgkm domain)
        v16f acc0 = (v16f)(0.0f), acc1 = (v16f)(0.0f);
#pragma unroll
        for (int kt = 0; kt < 8; kt++) {
            int G = kt * 4 + 2 * h;
            uint4 y0 = *(const uint4*)(sB + nrow + (((G    ) ^ c) * 16));
            uint4 y1 = *(const uint4*)(sB + nrow + (((G + 1) ^ c) * 16));
            v8i b = (v8i){(int)y0.x, (int)y0.y, (int)y0.z, (int)y0.w,
                          (int)y1.x, (int)y1.y, (int)y1.z, (int)y1.w};
            if (kt & 1)
                acc1 = __builtin_amdgcn_mfma_scale_f32_32x32x64_f8f6f4(
                    za[kt], b, acc1, 0, 0, 0, 0x7F, 0, 0x7F);
            else
                acc0 = __builtin_amdgcn_mfma_scale_f32_32x32x64_f8f6f4(
                    za[kt], b, acc0, 0, 0, 0, 0x7F, 0, 0x7F);
        }

        unsigned n = (unsigned)(ct * 64 + wn * 32 + c);
#pragma unroll
        for (int reg = 0; reg < 16; reg++) {
            float s = en - (acc0[reg] + acc1[reg]) * EINV;
            unsigned kq = (unsigned)fmaf(s, KSCL, KOFF);   // trunc; monotone
            unsigned p = (kq << 12) | n;
            runmin[reg] = runmin[reg] < p ? runmin[reg] : p;
        }

        asm volatile("s_waitcnt lgkmcnt(0)" ::: "memory"); // ds reads of buf done
        __builtin_amdgcn_s_barrier();     // all waves done reading buf[ct&1]

        if (ct < 62) {                    // stage tile ct+2 into buf[ct&1]
            unsigned char* sD = (ct & 1) ? sB1 : sB0;
            const unsigned char* ebase = e8 + (size_t)(ct + 2) * 32768;
#pragma unroll
            for (int s = 0; s < 8; s++)
                gld16(ebase + eoff[s], sD + (wv * 8 + s) * 1024);
        }
    }

    // ---- cross-lane reduce (32 cols per half), then cross-wn combine via LDS
    __syncthreads();                      // done with buffers -> reuse as scratch
    unsigned* tmp = (unsigned*)sB0;       // [4 waves][32 rows]
#pragma unroll
    for (int reg = 0; reg < 16; reg++) {
        unsigned v = runmin[reg];
#pragma unroll
        for (int off = 1; off < 32; off <<= 1) {
            unsigned o = (unsigned)__shfl_xor((int)v, off);
            v = v < o ? v : o;
        }
        if (c == 0) {
            int rr = (reg & 3) + 8 * (reg >> 2) + 4 * h;   // row within 32-half
            tmp[(wm * 2 + wn) * 32 + rr] = v;
        }
    }
    __syncthreads();
    if (tid < 64) {                       // row br = tid: combine the two wn halves
        int wmb = tid >> 5, rr = tid & 31;
        unsigned v0 = tmp[(wmb * 2 + 0) * 32 + rr];
        unsigned v1 = tmp[(wmb * 2 + 1) * 32 + rr];
        rowmin[row0 + tid] = v0 < v1 ? v0 : v1;
    }
}

// ---------------- 4. gather + STE output + sse + hist -------------
__global__ void gather_loss(const float* __restrict__ z, const float* __restrict__ emb,
                            const unsigned* __restrict__ rowmin,
                            float* __restrict__ out, double* __restrict__ sse,
                            unsigned* __restrict__ counts) {
    int i = blockIdx.x * blockDim.x + threadIdx.x;   // f4 index, 4194304 total
    float4 zv = ((const float4*)z)[i];
    int row = i >> 7, col = i & 127;
    unsigned code = rowmin[row] & 0xFFFu;
    if (col == 0) atomicAdd(&counts[code], 1u);      // fused histogram: one lane per row
    float4 q = ((const float4*)emb)[code * 128 + col];
    float4 dv = make_float4(q.x - zv.x, q.y - zv.y, q.z - zv.z, q.w - zv.w);
    float4 o  = make_float4(zv.x + dv.x, zv.y + dv.y, zv.z + dv.z, zv.w + dv.w);
    ((float4*)out)[i] = o;
    double loc = (double)dv.x*dv.x + (double)dv.y*dv.y + (double)dv.z*dv.z + (double)dv.w*dv.w;
    for (int off = 32; off; off >>= 1) loc += __shfl_down(loc, off);
    __shared__ double sw[4];
    if ((threadIdx.x & 63) == 0) sw[threadIdx.x >> 6] = loc;
    __syncthreads();
    if (threadIdx.x == 0)
        atomicAdd(&sse[blockIdx.x & 255], sw[0] + sw[1] + sw[2] + sw[3]);  // 256 slots
}

// ---------------- 5. losses + perplexity -------------
__global__ void finalize(const unsigned* __restrict__ counts, const double* __restrict__ sse,
                         float* __restrict__ out) {
    __shared__ double sh[256], sv[256];
    double h = 0.0;
    for (int b = threadIdx.x; b < NCODE; b += 256) {
        double p = (double)counts[b] / (double)NTOK;
        h += p * log(p + 1e-10);
    }
    sh[threadIdx.x] = h;
    sv[threadIdx.x] = sse[threadIdx.x];
    __syncthreads();
    for (int off = 128; off > 0; off >>= 1) {
        if (threadIdx.x < off) {
            sh[threadIdx.x] += sh[threadIdx.x + off];
            sv[threadIdx.x] += sv[threadIdx.x + off];
        }
        __syncthreads();
    }
    if (threadIdx.x == 0) {
        out[NELEM]     = (float)((1.0 + COMMIT) * sv[0] / (double)NELEM);  // vq_loss
        out[NELEM + 1] = (float)exp(-sh[0]);                                // perplexity
    }
}

// ---------------- launch ----------------
extern "C" void kernel_launch(void* const* d_in, const int* in_sizes, int n_in,
                              void* d_out, int out_size, void* d_ws, size_t ws_size,
                              hipStream_t stream) {
    const float* z   = (const float*)d_in[0];
    const float* emb = (const float*)d_in[1];
    float* out = (float*)d_out;
    char* ws = (char*)d_ws;

    unsigned* z8 = (unsigned*)(ws + OFF_Z8);
    unsigned* e8 = (unsigned*)(ws + OFF_E8);
    float*    en32 = (float*)(ws + OFF_EN32);
    unsigned* rowmin = (unsigned*)(ws + OFF_ROWMIN);
    unsigned* counts = (unsigned*)(ws + OFF_COUNTS);
    double*   sse    = (double*)(ws + OFF_SSE);

    conv_kernel<<<(NELEM/16 + (NCODE*DIM)/16 + 255) / 256, 256, 0, stream>>>(
        z, emb, z8, e8, counts, sse);
    enorm_kernel<<<(NCODE * 64) / 256, 256, 0, stream>>>(emb, en32);

    score_pass<<<NTOK / 64, 256, 0, stream>>>((const unsigned char*)z8,
                                              (const unsigned char*)e8, en32, rowmin);

    gather_loss<<<NELEM / 4 / 256, 256, 0, stream>>>(z, emb, rowmin, out, sse, counts);
    finalize<<<1, 256, 0, stream>>>(counts, sse, out);
}